// Round 1
// baseline (94.439 us; speedup 1.0000x reference)
//
#include <hip/hip_runtime.h>

#define C_CLS 21
#define RPB 128  // rois per block in softmax kernel

// ---------------------------------------------------------------------------
// Kernel 1: per-(roi,class) bbox decode + clip.
// One float4 load from roi_cls_loc, one float4 load of rois[r] (broadcast
// across the 21 classes of a roi, L1-cached), one float4 store.
// ---------------------------------------------------------------------------
__global__ __launch_bounds__(256) void bbox_kernel(
    const float4* __restrict__ rois,      // (R) float4
    const float4* __restrict__ loc,       // (R*C) float4
    float4* __restrict__ out,             // (R*C) float4
    int total)                            // R*C
{
    const int stride = gridDim.x * blockDim.x;
    for (int idx = blockIdx.x * blockDim.x + threadIdx.x; idx < total; idx += stride) {
        const int r = idx / C_CLS;          // magic-mul div by 21
        const float4 roi = rois[r];
        const float4 l  = loc[idx];

        const float src_h  = roi.z - roi.x;
        const float src_w  = roi.w - roi.y;
        const float src_cy = roi.x + 0.5f * src_h;
        const float src_cx = roi.y + 0.5f * src_w;

        // LOC_STD = [0.1, 0.1, 0.2, 0.2], mean = 0
        const float dy = l.x * 0.1f;
        const float dx = l.y * 0.1f;
        const float dh = l.z * 0.2f;
        const float dw = l.w * 0.2f;

        const float cy = dy * src_h + src_cy;
        const float cx = dx * src_w + src_cx;
        const float h  = __expf(dh) * src_h;
        const float w  = __expf(dw) * src_w;

        float4 o;
        o.x = fminf(fmaxf(cy - 0.5f * h, 0.0f), 600.0f);
        o.y = fminf(fmaxf(cx - 0.5f * w, 0.0f), 800.0f);
        o.z = fminf(fmaxf(cy + 0.5f * h, 0.0f), 600.0f);
        o.w = fminf(fmaxf(cx + 0.5f * w, 0.0f), 800.0f);
        out[idx] = o;
    }
}

// ---------------------------------------------------------------------------
// Kernel 2: row softmax over C=21 classes.
// RPB rois per block: coalesced float4 staging into LDS, per-thread row
// softmax (LDS stride 21 floats is odd -> conflict-free), coalesced store.
// ---------------------------------------------------------------------------
__global__ __launch_bounds__(RPB) void softmax_kernel(
    const float* __restrict__ scores,     // (R, C)
    float* __restrict__ prob,             // (R, C)
    int nrois)
{
    __shared__ float lds[RPB * C_CLS];

    const int base_roi = blockIdx.x * RPB;
    const int count = min(RPB, nrois - base_roi);
    const int n = count * C_CLS;                 // floats handled by this block
    const int base = base_roi * C_CLS;

    // --- stage in (vector path when n divisible by 4; base is 16B-aligned:
    //     base*4 = blk*128*21*4 = blk*10752 bytes) ---
    if ((n & 3) == 0) {
        const float4* src = (const float4*)(scores + base);
        float4* dst = (float4*)lds;
        const int n4 = n >> 2;
        for (int i = threadIdx.x; i < n4; i += RPB) dst[i] = src[i];
    } else {
        for (int i = threadIdx.x; i < n; i += RPB) lds[i] = scores[base + i];
    }
    __syncthreads();

    // --- per-thread row softmax ---
    const int t = threadIdx.x;
    if (t < count) {
        float* row = &lds[t * C_CLS];
        float m = row[0];
#pragma unroll
        for (int i = 1; i < C_CLS; ++i) m = fmaxf(m, row[i]);
        float e[C_CLS];
        float s = 0.0f;
#pragma unroll
        for (int i = 0; i < C_CLS; ++i) { e[i] = __expf(row[i] - m); s += e[i]; }
        const float inv = 1.0f / s;
#pragma unroll
        for (int i = 0; i < C_CLS; ++i) row[i] = e[i] * inv;
    }
    __syncthreads();

    // --- stage out ---
    if ((n & 3) == 0) {
        const float4* src = (const float4*)lds;
        float4* dst = (float4*)(prob + base);
        const int n4 = n >> 2;
        for (int i = threadIdx.x; i < n4; i += RPB) dst[i] = src[i];
    } else {
        for (int i = threadIdx.x; i < n; i += RPB) prob[base + i] = lds[i];
    }
}

extern "C" void kernel_launch(void* const* d_in, const int* in_sizes, int n_in,
                              void* d_out, int out_size, void* d_ws, size_t ws_size,
                              hipStream_t stream) {
    const float* rois   = (const float*)d_in[0];   // (R,4)
    const float* loc    = (const float*)d_in[1];   // (R, C*4)
    const float* scores = (const float*)d_in[2];   // (R, C)
    float* out = (float*)d_out;

    const int R = in_sizes[0] / 4;
    const int total = R * C_CLS;                   // (roi,class) pairs

    float* bbox_out = out;                          // R*C*4 floats
    float* prob_out = out + (size_t)total * 4;      // R*C floats, 16B-aligned

    bbox_kernel<<<2048, 256, 0, stream>>>(
        (const float4*)rois, (const float4*)loc, (float4*)bbox_out, total);

    const int sblocks = (R + RPB - 1) / RPB;
    softmax_kernel<<<sblocks, RPB, 0, stream>>>(scores, prob_out, R);
}

// Round 2
// 74.139 us; speedup vs baseline: 1.2738x; 1.2738x over previous
//
#include <hip/hip_runtime.h>

#define C_CLS 21
#define RPB 256          // rois per softmax block
#define PAIRS_PER_BLK 1024  // bbox pairs per block (4 per thread, 256 threads)

typedef float f4 __attribute__((ext_vector_type(4)));

// ---------------------------------------------------------------------------
// Fused kernel. Blocks [0, nb_soft): row softmax over C=21.
//                Blocks [nb_soft, ...): bbox decode+clip, 4 (roi,class)
//                pairs per thread for memory-level parallelism.
// Nontemporal hints on all streamed (read-once / write-once) data.
// ---------------------------------------------------------------------------
__global__ __launch_bounds__(256) void fused_kernel(
    const f4* __restrict__ rois,        // (R) float4 — reused 21x, keep cached
    const f4* __restrict__ loc,         // (R*C) float4 — streamed
    const float* __restrict__ scores,   // (R*C) floats — streamed
    f4* __restrict__ bbox_out,          // (R*C) float4 — streamed
    float* __restrict__ prob_out,       // (R*C) floats — streamed
    int total,                          // R*C pairs
    int nrois,                          // R
    int nb_soft)
{
    __shared__ float lds[RPB * C_CLS];  // 21504 B

    if ((int)blockIdx.x < nb_soft) {
        // ------------------------- softmax part -------------------------
        const int base_roi = blockIdx.x * RPB;
        const int count = min(RPB, nrois - base_roi);
        const int n = count * C_CLS;
        const long base = (long)base_roi * C_CLS;

        if ((n & 3) == 0) {
            const f4* src = (const f4*)(scores + base);
            f4* dst = (f4*)lds;
            const int n4 = n >> 2;
            for (int i = threadIdx.x; i < n4; i += RPB)
                dst[i] = __builtin_nontemporal_load(src + i);
        } else {
            for (int i = threadIdx.x; i < n; i += RPB)
                lds[i] = scores[base + i];
        }
        __syncthreads();

        const int t = threadIdx.x;
        if (t < count) {
            float* row = &lds[t * C_CLS];
            float m = row[0];
#pragma unroll
            for (int i = 1; i < C_CLS; ++i) m = fmaxf(m, row[i]);
            float e[C_CLS];
            float s = 0.0f;
#pragma unroll
            for (int i = 0; i < C_CLS; ++i) { e[i] = __expf(row[i] - m); s += e[i]; }
            const float inv = 1.0f / s;
#pragma unroll
            for (int i = 0; i < C_CLS; ++i) row[i] = e[i] * inv;
        }
        __syncthreads();

        if ((n & 3) == 0) {
            const f4* src = (const f4*)lds;
            f4* dst = (f4*)(prob_out + base);
            const int n4 = n >> 2;
            for (int i = threadIdx.x; i < n4; i += RPB)
                __builtin_nontemporal_store(src[i], dst + i);
        } else {
            for (int i = threadIdx.x; i < n; i += RPB)
                prob_out[base + i] = lds[i];
        }
    } else {
        // -------------------------- bbox part ---------------------------
        const int base = (blockIdx.x - nb_soft) * PAIRS_PER_BLK + threadIdx.x;
#pragma unroll
        for (int k = 0; k < 4; ++k) {
            const int idx = base + k * 256;
            if (idx < total) {
                const int r = idx / C_CLS;           // magic-mul div
                const f4 roi = rois[r];              // cached (21x reuse)
                const f4 l = __builtin_nontemporal_load(loc + idx);

                const float src_h  = roi.z - roi.x;
                const float src_w  = roi.w - roi.y;
                const float src_cy = roi.x + 0.5f * src_h;
                const float src_cx = roi.y + 0.5f * src_w;

                const float dy = l.x * 0.1f;
                const float dx = l.y * 0.1f;
                const float dh = l.z * 0.2f;
                const float dw = l.w * 0.2f;

                const float cy = dy * src_h + src_cy;
                const float cx = dx * src_w + src_cx;
                const float h  = __expf(dh) * src_h;
                const float w  = __expf(dw) * src_w;

                f4 o;
                o.x = fminf(fmaxf(cy - 0.5f * h, 0.0f), 600.0f);
                o.y = fminf(fmaxf(cx - 0.5f * w, 0.0f), 800.0f);
                o.z = fminf(fmaxf(cy + 0.5f * h, 0.0f), 600.0f);
                o.w = fminf(fmaxf(cx + 0.5f * w, 0.0f), 800.0f);
                __builtin_nontemporal_store(o, bbox_out + idx);
            }
        }
    }
}

extern "C" void kernel_launch(void* const* d_in, const int* in_sizes, int n_in,
                              void* d_out, int out_size, void* d_ws, size_t ws_size,
                              hipStream_t stream) {
    const float* rois   = (const float*)d_in[0];   // (R,4)
    const float* loc    = (const float*)d_in[1];   // (R, C*4)
    const float* scores = (const float*)d_in[2];   // (R, C)
    float* out = (float*)d_out;

    const int R = in_sizes[0] / 4;
    const int total = R * C_CLS;

    float* bbox_out = out;                          // R*C*4 floats
    float* prob_out = out + (size_t)total * 4;      // R*C floats

    const int nb_soft = (R + RPB - 1) / RPB;
    const int nb_bbox = (total + PAIRS_PER_BLK - 1) / PAIRS_PER_BLK;

    fused_kernel<<<nb_soft + nb_bbox, 256, 0, stream>>>(
        (const f4*)rois, (const f4*)loc, scores,
        (f4*)bbox_out, prob_out, total, R, nb_soft);
}

// Round 3
// 73.587 us; speedup vs baseline: 1.2834x; 1.0075x over previous
//
#include <hip/hip_runtime.h>

#define C_CLS 21
#define RPB 256             // rois per softmax block
#define PPT 8               // bbox pairs per thread
#define PAIRS_PER_BLK (256 * PPT)

typedef float f4 __attribute__((ext_vector_type(4)));

__device__ __forceinline__ f4 decode_one(const f4 roi, const f4 l) {
    const float src_h  = roi.z - roi.x;
    const float src_w  = roi.w - roi.y;
    const float src_cy = roi.x + 0.5f * src_h;
    const float src_cx = roi.y + 0.5f * src_w;

    const float dy = l.x * 0.1f;
    const float dx = l.y * 0.1f;
    const float dh = l.z * 0.2f;
    const float dw = l.w * 0.2f;

    const float cy = dy * src_h + src_cy;
    const float cx = dx * src_w + src_cx;
    const float h  = __expf(dh) * src_h;
    const float w  = __expf(dw) * src_w;

    f4 o;
    o.x = fminf(fmaxf(cy - 0.5f * h, 0.0f), 600.0f);
    o.y = fminf(fmaxf(cx - 0.5f * w, 0.0f), 800.0f);
    o.z = fminf(fmaxf(cy + 0.5f * h, 0.0f), 600.0f);
    o.w = fminf(fmaxf(cx + 0.5f * w, 0.0f), 800.0f);
    return o;
}

// ---------------------------------------------------------------------------
// Fused kernel. Blocks [0, nb_soft): row softmax over C=21.
//                Blocks [nb_soft, ...): bbox decode+clip, 8 pairs/thread.
// Full bbox blocks take an unguarded path: 8 NT loads issued back-to-back,
// then compute+store. Only the last block runs the guarded loop.
// ---------------------------------------------------------------------------
__global__ __launch_bounds__(256) void fused_kernel(
    const f4* __restrict__ rois,        // (R) float4 — reused 21x, cached
    const f4* __restrict__ loc,         // (R*C) float4 — streamed
    const float* __restrict__ scores,   // (R*C) floats — streamed
    f4* __restrict__ bbox_out,          // (R*C) float4 — streamed
    float* __restrict__ prob_out,       // (R*C) floats — streamed
    int total,                          // R*C pairs
    int nrois,                          // R
    int nb_soft)
{
    __shared__ float lds[RPB * C_CLS];  // 21504 B

    if ((int)blockIdx.x < nb_soft) {
        // ------------------------- softmax part -------------------------
        const int base_roi = blockIdx.x * RPB;
        const int count = min(RPB, nrois - base_roi);
        const int n = count * C_CLS;
        const long base = (long)base_roi * C_CLS;

        if ((n & 3) == 0) {
            const f4* src = (const f4*)(scores + base);
            f4* dst = (f4*)lds;
            const int n4 = n >> 2;
            for (int i = threadIdx.x; i < n4; i += RPB)
                dst[i] = __builtin_nontemporal_load(src + i);
        } else {
            for (int i = threadIdx.x; i < n; i += RPB)
                lds[i] = scores[base + i];
        }
        __syncthreads();

        const int t = threadIdx.x;
        if (t < count) {
            float* row = &lds[t * C_CLS];
            float m = row[0];
#pragma unroll
            for (int i = 1; i < C_CLS; ++i) m = fmaxf(m, row[i]);
            float e[C_CLS];
            float s = 0.0f;
#pragma unroll
            for (int i = 0; i < C_CLS; ++i) { e[i] = __expf(row[i] - m); s += e[i]; }
            const float inv = 1.0f / s;
#pragma unroll
            for (int i = 0; i < C_CLS; ++i) row[i] = e[i] * inv;
        }
        __syncthreads();

        if ((n & 3) == 0) {
            const f4* src = (const f4*)lds;
            f4* dst = (f4*)(prob_out + base);
            const int n4 = n >> 2;
            for (int i = threadIdx.x; i < n4; i += RPB)
                __builtin_nontemporal_store(src[i], dst + i);
        } else {
            for (int i = threadIdx.x; i < n; i += RPB)
                prob_out[base + i] = lds[i];
        }
    } else {
        // -------------------------- bbox part ---------------------------
        const int blk = blockIdx.x - nb_soft;
        const int base = blk * PAIRS_PER_BLK + threadIdx.x;

        if (blk * PAIRS_PER_BLK + PAIRS_PER_BLK <= total) {
            // Uniform fast path: issue all 8 loads unconditionally.
            f4 l[PPT], roi[PPT];
#pragma unroll
            for (int k = 0; k < PPT; ++k)
                l[k] = __builtin_nontemporal_load(loc + (base + k * 256));
#pragma unroll
            for (int k = 0; k < PPT; ++k)
                roi[k] = rois[(base + k * 256) / C_CLS];
#pragma unroll
            for (int k = 0; k < PPT; ++k) {
                const f4 o = decode_one(roi[k], l[k]);
                __builtin_nontemporal_store(o, bbox_out + (base + k * 256));
            }
        } else {
#pragma unroll
            for (int k = 0; k < PPT; ++k) {
                const int idx = base + k * 256;
                if (idx < total) {
                    const f4 o = decode_one(rois[idx / C_CLS],
                                            __builtin_nontemporal_load(loc + idx));
                    __builtin_nontemporal_store(o, bbox_out + idx);
                }
            }
        }
    }
}

extern "C" void kernel_launch(void* const* d_in, const int* in_sizes, int n_in,
                              void* d_out, int out_size, void* d_ws, size_t ws_size,
                              hipStream_t stream) {
    const float* rois   = (const float*)d_in[0];   // (R,4)
    const float* loc    = (const float*)d_in[1];   // (R, C*4)
    const float* scores = (const float*)d_in[2];   // (R, C)
    float* out = (float*)d_out;

    const int R = in_sizes[0] / 4;
    const int total = R * C_CLS;

    float* bbox_out = out;                          // R*C*4 floats
    float* prob_out = out + (size_t)total * 4;      // R*C floats

    const int nb_soft = (R + RPB - 1) / RPB;
    const int nb_bbox = (total + PAIRS_PER_BLK - 1) / PAIRS_PER_BLK;

    fused_kernel<<<nb_soft + nb_bbox, 256, 0, stream>>>(
        (const f4*)rois, (const f4*)loc, scores,
        (f4*)bbox_out, prob_out, total, R, nb_soft);
}